// Round 7
// baseline (94.053 us; speedup 1.0000x reference)
//
#include <hip/hip_runtime.h>

// sample_pdf (NeRF, det=True) — rank-scan gather, all-DPP lane ops, 4 rays/wave.
//
// u_j=(2j+1)/256 fixed grid; g(c)=ceil((256c-1)/2)=#{j:u_j<c}. Interval
// k=[cdf[k],cdf[k+1]) owns sample slots [g_k,g_{k+1}); K(j)=max{k: g_k<=j}
// == searchsorted(cdf,u_j,right)-1. Per ray: paint interval index at its
// start slot (atomicMax, only if g<NS), store params (A,B) with
// sample = A + u*B packed as float2, wave max-scan recovers K(j), gather+fma.
//
// All cross-lane ops are DPP (VALU, ~2cyc) — zero ds_bpermute:
//   scan:        row_shr:1/2/4/8 + row_bcast:15 (rows 1,3) + row_bcast:31 (rows 2,3)
//   shfl_down 1: wave_shl:1 (0x130), bound_ctrl -> lane 63 = 0 (unused)
//   shfl_up   1: wave_shr:1 (0x138), bound_ctrl -> lane  0 = 0 (exactly what e needs)

#define M     126
#define NBINS 127
#define NS    128
#define RPW   4     // rays per wave (independent chains for latency hiding)

template<int CTRL, int RM>
__device__ __forceinline__ float dpp_f(float x) {
    return __builtin_bit_cast(float,
        __builtin_amdgcn_update_dpp(0, __builtin_bit_cast(int, x),
                                    CTRL, RM, 0xf, true));
}
template<int CTRL, int RM>
__device__ __forceinline__ int dpp_i(int x) {
    return __builtin_amdgcn_update_dpp(0, x, CTRL, RM, 0xf, true);
}

__device__ __forceinline__ float wave_iscan_add(float x) {
    x += dpp_f<0x111, 0xf>(x);   // row_shr:1
    x += dpp_f<0x112, 0xf>(x);   // row_shr:2
    x += dpp_f<0x114, 0xf>(x);   // row_shr:4
    x += dpp_f<0x118, 0xf>(x);   // row_shr:8
    x += dpp_f<0x142, 0xa>(x);   // row_bcast:15 -> rows 1,3
    x += dpp_f<0x143, 0xc>(x);   // row_bcast:31 -> rows 2,3
    return x;
}
__device__ __forceinline__ int wave_iscan_max(int x) {
    x = max(x, dpp_i<0x111, 0xf>(x));
    x = max(x, dpp_i<0x112, 0xf>(x));
    x = max(x, dpp_i<0x114, 0xf>(x));
    x = max(x, dpp_i<0x118, 0xf>(x));
    x = max(x, dpp_i<0x142, 0xa>(x));
    x = max(x, dpp_i<0x143, 0xc>(x));
    return x;
}

__global__ __launch_bounds__(256) void sample_pdf_rank4(
    const float* __restrict__ bins,
    const float* __restrict__ weights,
    float* __restrict__ out,
    int n_rays)
{
    __shared__ int    s_idx[4 * RPW][NS];
    __shared__ float2 s_AB[4 * RPW][NS];   // (A, B): sample = A + u*B

    const int wave = threadIdx.x >> 6;
    const int lane = threadIdx.x & 63;
    const int base = (blockIdx.x * 4 + wave) * RPW;

    bool  valid[RPW];
    float b_a[RPW], b_b[RPW], w0[RPW], w1[RPW];

    // ---- zero-init this wave's paint region (RPW segs x 512B = 2KB) ----
    {
        const int4 z = make_int4(0, 0, 0, 0);
        char* p = (char*)&s_idx[wave * RPW][0];
        *reinterpret_cast<int4*>(p + lane * 16)        = z;
        *reinterpret_cast<int4*>(p + lane * 16 + 1024) = z;
    }

    // ---- phase A: all global loads issued up front ----
    #pragma unroll
    for (int r = 0; r < RPW; ++r) {
        int ry = base + r;
        valid[r] = (ry < n_rays);
        if (!valid[r]) ry = 0;
        const float* wrow = weights + (size_t)ry * M;
        const float* brow = bins    + (size_t)ry * NBINS;
        if (lane < 63) {
            b_a[r] = brow[2 * lane];
            b_b[r] = brow[2 * lane + 1];
            float2 ww = *reinterpret_cast<const float2*>(wrow + 2 * lane);
            w0[r] = ww.x + 1e-5f;
            w1[r] = ww.y + 1e-5f;
        } else {
            b_a[r] = brow[126];          // feeds lane 62's b_c via wave_shl:1
            b_b[r] = 0.0f; w0[r] = 0.0f; w1[r] = 0.0f;
        }
    }
    __builtin_amdgcn_wave_barrier();

    // ---- phase B: scan -> cdf -> ranks -> params -> paint ----
    #pragma unroll
    for (int r = 0; r < RPW; ++r) {
        const float b_c   = dpp_f<0x130, 0xf>(b_a[r]);     // bins[2i+2]
        const float pair  = w0[r] + w1[r];
        const float ps    = wave_iscan_add(pair);          // inclusive prefix
        const float total = __shfl(ps, 63, 64);            // readlane
        const float inv   = __builtin_amdgcn_rcpf(total);
        const float excl  = ps - pair;
        const float c0 = excl * inv;                       // cdf[2i]
        const float c1 = (excl + w0[r]) * inv;             // cdf[2i+1]
        const float c2 = ps * inv;                         // cdf[2i+2]

        int g0 = (int)ceilf(fmaf(c0, 256.0f, -1.0f) * 0.5f);
        int g1 = (int)ceilf(fmaf(c1, 256.0f, -1.0f) * 0.5f);
        if (lane == 63) { g0 = NS; g1 = NS; }              // owns no intervals
        g0 = max(g0, 0);
        g1 = max(g1, 0);

        float dA = c1 - c0; dA = (dA < 1e-5f) ? 1.0f : dA;
        float dB = c2 - c1; dB = (dB < 1e-5f) ? 1.0f : dB;
        const float slA = (b_b[r] - b_a[r]) * __builtin_amdgcn_rcpf(dA);
        const float slB = (b_c    - b_b[r]) * __builtin_amdgcn_rcpf(dB);
        const float A0  = fmaf(-c0, slA, b_a[r]);          // bl - cl*sl
        const float A1  = fmaf(-c1, slB, b_b[r]);

        const int seg = wave * RPW + r;
        *reinterpret_cast<float4*>(&s_AB[seg][2 * lane]) =
            make_float4(A0, slA, A1, slB);                 // one ds_write_b128
        if (g0 < NS) atomicMax(&s_idx[seg][g0], 2 * lane);
        if (g1 < NS) atomicMax(&s_idx[seg][g1], 2 * lane + 1);
    }
    __builtin_amdgcn_wave_barrier();

    // ---- phase C: max-scan K(j), gather, interpolate, store ----
    #pragma unroll
    for (int r = 0; r < RPW; ++r) {
        const int seg = wave * RPW + r;
        const int2 xi = *reinterpret_cast<const int2*>(&s_idx[seg][2 * lane]);
        const int  m  = wave_iscan_max(max(xi.x, xi.y));
        const int  e  = dpp_i<0x138, 0xf>(m);   // prev slot-pair max; lane0 -> 0
        const int  K0 = max(e, xi.x);           // interval of sample 2*lane
        const int  K1 = max(K0, xi.y);          // interval of sample 2*lane+1

        const float2 ab0 = s_AB[seg][K0];       // ds_read_b64 gather
        const float2 ab1 = s_AB[seg][K1];
        const float u0 = fmaf((float)lane, 0.015625f, 0.00390625f); // (4l+1)/256
        const float u1 = u0 + 0.0078125f;                           // (4l+3)/256
        float2 res;
        res.x = fmaf(u0, ab0.y, ab0.x);
        res.y = fmaf(u1, ab1.y, ab1.x);
        if (valid[r])
            *reinterpret_cast<float2*>(out + (size_t)(base + r) * NS + 2 * lane) = res;
    }
}

extern "C" void kernel_launch(void* const* d_in, const int* in_sizes, int n_in,
                              void* d_out, int out_size, void* d_ws, size_t ws_size,
                              hipStream_t stream) {
    const float* bins    = (const float*)d_in[0];
    const float* weights = (const float*)d_in[1];
    float* out = (float*)d_out;

    const int n_rays = in_sizes[0] / NBINS;
    const int rays_per_block = 4 * RPW;
    const int blocks = (n_rays + rays_per_block - 1) / rays_per_block;
    sample_pdf_rank4<<<blocks, 256, 0, stream>>>(bins, weights, out, n_rays);
}

// Round 8
// 87.172 us; speedup vs baseline: 1.0789x; 1.0789x over previous
//
#include <hip/hip_runtime.h>

// sample_pdf (NeRF, det=True) — rank-scan gather, 2 rays/wave, all-DPP lane ops,
// round-6 memory layout (SoA float2 stores = stride-8B = conflict-free).
//
// u_j=(2j+1)/256 fixed grid; g(c)=ceil((256c-1)/2)=#{j:u_j<c}. Interval
// k=[cdf[k],cdf[k+1]) owns sample slots [g_k,g_{k+1}); K(j)=max{k: g_k<=j}
// == searchsorted(cdf,u_j,right)-1. Per ray: atomicMax-paint interval index k
// at its start slot (only if g<NS; empty-past-end intervals own nothing),
// store params (A,B) with sample = A + u*B, wave max-scan forward-fills K(j),
// gather + fma + store. atomicMax (not plain write) is required: ulp
// disagreement between lanes' g versions can collide two paints at one slot,
// and wrong-order overwrite would extrapolate a stale interval over a span.
//
// All cross-lane ops are DPP (pure VALU, no ds_bpermute):
//   scan:         row_shr:1/2/4/8 + row_bcast:15 (rows 1,3) + row_bcast:31 (rows 2,3)
//   shfl_down(1): wave_shl:1 (0x130)  [HW-validated round 7]
//   shfl_up(1):   wave_shr:1 (0x138), bound_ctrl -> lane 0 reads 0 (= the e we need)

#define M     126
#define NBINS 127
#define NS    128
#define RPW   2     // rays per wave

template<int CTRL, int RM>
__device__ __forceinline__ float dpp_f(float x) {
    return __builtin_bit_cast(float,
        __builtin_amdgcn_update_dpp(0, __builtin_bit_cast(int, x),
                                    CTRL, RM, 0xf, true));
}
template<int CTRL, int RM>
__device__ __forceinline__ int dpp_i(int x) {
    return __builtin_amdgcn_update_dpp(0, x, CTRL, RM, 0xf, true);
}

__device__ __forceinline__ float wave_iscan_add(float x) {
    x += dpp_f<0x111, 0xf>(x);   // row_shr:1
    x += dpp_f<0x112, 0xf>(x);   // row_shr:2
    x += dpp_f<0x114, 0xf>(x);   // row_shr:4
    x += dpp_f<0x118, 0xf>(x);   // row_shr:8
    x += dpp_f<0x142, 0xa>(x);   // row_bcast:15 -> rows 1,3
    x += dpp_f<0x143, 0xc>(x);   // row_bcast:31 -> rows 2,3
    return x;
}
__device__ __forceinline__ int wave_iscan_max(int x) {
    x = max(x, dpp_i<0x111, 0xf>(x));
    x = max(x, dpp_i<0x112, 0xf>(x));
    x = max(x, dpp_i<0x114, 0xf>(x));
    x = max(x, dpp_i<0x118, 0xf>(x));
    x = max(x, dpp_i<0x142, 0xa>(x));
    x = max(x, dpp_i<0x143, 0xc>(x));
    return x;
}

__global__ __launch_bounds__(256) void sample_pdf_rank8(
    const float* __restrict__ bins,
    const float* __restrict__ weights,
    float* __restrict__ out,
    int n_rays)
{
    __shared__ int   s_idx[4 * RPW][NS];
    __shared__ float s_A[4 * RPW][NS];   // A = bl - cl*sl
    __shared__ float s_B[4 * RPW][NS];   // B = sl

    const int wave = threadIdx.x >> 6;
    const int lane = threadIdx.x & 63;
    const int base = (blockIdx.x * 4 + wave) * RPW;

    bool  valid[RPW];
    float b_a[RPW], b_b[RPW], w0[RPW], w1[RPW];

    // ---- phase A: global loads (both rays in flight) + paint-slot init ----
    #pragma unroll
    for (int r = 0; r < RPW; ++r) {
        int ry = base + r;
        valid[r] = (ry < n_rays);
        if (!valid[r]) ry = 0;
        const float* wrow = weights + (size_t)ry * M;
        const float* brow = bins    + (size_t)ry * NBINS;
        if (lane < 63) {
            b_a[r] = brow[2 * lane];
            b_b[r] = brow[2 * lane + 1];
            float2 ww = *reinterpret_cast<const float2*>(wrow + 2 * lane);
            w0[r] = ww.x + 1e-5f;
            w1[r] = ww.y + 1e-5f;
        } else {
            b_a[r] = brow[126];          // feeds lane 62's b_c via wave_shl:1
            b_b[r] = 0.0f; w0[r] = 0.0f; w1[r] = 0.0f;
        }
        const int seg = wave * RPW + r;
        *reinterpret_cast<int2*>(&s_idx[seg][2 * lane]) = make_int2(0, 0);
    }
    __builtin_amdgcn_wave_barrier();

    // ---- phase B: scan -> cdf -> ranks -> params -> paint ----
    #pragma unroll
    for (int r = 0; r < RPW; ++r) {
        const float b_c   = dpp_f<0x130, 0xf>(b_a[r]);     // bins[2i+2]
        const float pair  = w0[r] + w1[r];
        const float ps    = wave_iscan_add(pair);          // inclusive prefix
        const float total = __shfl(ps, 63, 64);            // v_readlane
        const float inv   = __builtin_amdgcn_rcpf(total);
        const float excl  = ps - pair;
        const float c0 = excl * inv;                       // cdf[2i]
        const float c1 = (excl + w0[r]) * inv;             // cdf[2i+1]
        const float c2 = ps * inv;                         // cdf[2i+2]

        int g0 = (int)ceilf(fmaf(c0, 256.0f, -1.0f) * 0.5f);
        int g1 = (int)ceilf(fmaf(c1, 256.0f, -1.0f) * 0.5f);
        if (lane == 63) { g0 = NS; g1 = NS; }              // owns no intervals
        g0 = max(g0, 0);
        g1 = max(g1, 0);

        float dA = c1 - c0; dA = (dA < 1e-5f) ? 1.0f : dA;
        float dB = c2 - c1; dB = (dB < 1e-5f) ? 1.0f : dB;
        const float slA = (b_b[r] - b_a[r]) * __builtin_amdgcn_rcpf(dA);
        const float slB = (b_c    - b_b[r]) * __builtin_amdgcn_rcpf(dB);
        const float A0  = fmaf(-c0, slA, b_a[r]);          // bl - cl*sl
        const float A1  = fmaf(-c1, slB, b_b[r]);

        const int seg = wave * RPW + r;
        // SoA float2 stores: stride 8B across lanes -> 2-way bank alias (free)
        *reinterpret_cast<float2*>(&s_A[seg][2 * lane]) = make_float2(A0, A1);
        *reinterpret_cast<float2*>(&s_B[seg][2 * lane]) = make_float2(slA, slB);
        if (g0 < NS) atomicMax(&s_idx[seg][g0], 2 * lane);
        if (g1 < NS) atomicMax(&s_idx[seg][g1], 2 * lane + 1);
    }
    __builtin_amdgcn_wave_barrier();

    // ---- phase C: max-scan K(j), gather, interpolate, store ----
    #pragma unroll
    for (int r = 0; r < RPW; ++r) {
        const int seg = wave * RPW + r;
        const int2 xi = *reinterpret_cast<const int2*>(&s_idx[seg][2 * lane]);
        const int  m  = wave_iscan_max(max(xi.x, xi.y));
        const int  e  = dpp_i<0x138, 0xf>(m);   // prev pair's max; lane 0 -> 0
        const int  K0 = max(e, xi.x);           // interval of sample 2*lane
        const int  K1 = max(K0, xi.y);          // interval of sample 2*lane+1

        const float A0 = s_A[seg][K0], B0 = s_B[seg][K0];
        const float A1 = s_A[seg][K1], B1 = s_B[seg][K1];
        const float u0 = fmaf((float)lane, 0.015625f, 0.00390625f); // (4l+1)/256
        const float u1 = u0 + 0.0078125f;                           // (4l+3)/256
        float2 res;
        res.x = fmaf(u0, B0, A0);
        res.y = fmaf(u1, B1, A1);
        if (valid[r])
            *reinterpret_cast<float2*>(out + (size_t)(base + r) * NS + 2 * lane) = res;
    }
}

extern "C" void kernel_launch(void* const* d_in, const int* in_sizes, int n_in,
                              void* d_out, int out_size, void* d_ws, size_t ws_size,
                              hipStream_t stream) {
    const float* bins    = (const float*)d_in[0];
    const float* weights = (const float*)d_in[1];
    float* out = (float*)d_out;

    const int n_rays = in_sizes[0] / NBINS;
    const int rays_per_block = 4 * RPW;
    const int blocks = (n_rays + rays_per_block - 1) / rays_per_block;
    sample_pdf_rank8<<<blocks, 256, 0, stream>>>(bins, weights, out, n_rays);
}

// Round 9
// 81.586 us; speedup vs baseline: 1.1528x; 1.0685x over previous
//
#include <hip/hip_runtime.h>

// sample_pdf (NeRF, det=True) — rank-scan gather, 3 rays/wave, all-DPP lane
// ops, fused per-segment LDS layout [idx|A|B] (one base, imm offsets).
//
// u_j=(2j+1)/256 fixed grid; g(c)=ceil((256c-1)/2)=#{j:u_j<c}. Interval
// k=[cdf[k],cdf[k+1]) owns sample slots [g_k,g_{k+1}); K(j)=max{k: g_k<=j}
// == searchsorted(cdf,u_j,right)-1. Per ray: atomicMax-paint interval index k
// at its start slot (only if g<NS), store params (A,B) with sample = A + u*B,
// wave max-scan forward-fills K(j), gather + fma + store.
// RPW=3 -> 18 KB LDS/block: still 8 blocks/CU (144 KB <= 160 KB), unlike the
// RPW=4/24KB variant that dropped occupancy to 61% (round-7 regression).
//
// Cross-lane ops are DPP (pure VALU): scan = row_shr:1/2/4/8 + row_bcast:15
// (rows 1,3) + row_bcast:31 (rows 2,3); shfl_down(1)=wave_shl:1 (0x130);
// shfl_up(1)=wave_shr:1 (0x138, bound_ctrl gives lane0=0). All HW-validated
// in rounds 7-8.

#define M     126
#define NBINS 127
#define NS    128
#define RPW   3     // rays per wave

template<int CTRL, int RM>
__device__ __forceinline__ float dpp_f(float x) {
    return __builtin_bit_cast(float,
        __builtin_amdgcn_update_dpp(0, __builtin_bit_cast(int, x),
                                    CTRL, RM, 0xf, true));
}
template<int CTRL, int RM>
__device__ __forceinline__ int dpp_i(int x) {
    return __builtin_amdgcn_update_dpp(0, x, CTRL, RM, 0xf, true);
}

__device__ __forceinline__ float wave_iscan_add(float x) {
    x += dpp_f<0x111, 0xf>(x);   // row_shr:1
    x += dpp_f<0x112, 0xf>(x);   // row_shr:2
    x += dpp_f<0x114, 0xf>(x);   // row_shr:4
    x += dpp_f<0x118, 0xf>(x);   // row_shr:8
    x += dpp_f<0x142, 0xa>(x);   // row_bcast:15 -> rows 1,3
    x += dpp_f<0x143, 0xc>(x);   // row_bcast:31 -> rows 2,3
    return x;
}
__device__ __forceinline__ int wave_iscan_max(int x) {
    x = max(x, dpp_i<0x111, 0xf>(x));
    x = max(x, dpp_i<0x112, 0xf>(x));
    x = max(x, dpp_i<0x114, 0xf>(x));
    x = max(x, dpp_i<0x118, 0xf>(x));
    x = max(x, dpp_i<0x142, 0xa>(x));
    x = max(x, dpp_i<0x143, 0xc>(x));
    return x;
}

__global__ __launch_bounds__(256) void sample_pdf_rank9(
    const float* __restrict__ bins,
    const float* __restrict__ weights,
    float* __restrict__ out,
    int n_rays)
{
    // Fused per-segment layout: [0..127]=paint idx (int),
    // [128..255]=A (float), [256..383]=B (float).  18 KB total.
    __shared__ int s_all[4 * RPW][3 * NS];

    const int wave = threadIdx.x >> 6;
    const int lane = threadIdx.x & 63;
    const int base = (blockIdx.x * 4 + wave) * RPW;

    // ---- init paint slots (LDS; ordered vs later atomics by wave_barrier) ----
    #pragma unroll
    for (int r = 0; r < RPW; ++r)
        *reinterpret_cast<int2*>(&s_all[wave * RPW + r][2 * lane]) = make_int2(0, 0);

    // ---- phase A: all global loads up front; rcp(w) hoisted off-chain ----
    bool  valid[RPW];
    float b_a[RPW], b_b[RPW], w0[RPW], w1[RPW], rw0[RPW], rw1[RPW];
    #pragma unroll
    for (int r = 0; r < RPW; ++r) {
        int ry = base + r;
        valid[r] = (ry < n_rays);
        if (!valid[r]) ry = n_rays - 1;
        const float* wrow = weights + (size_t)ry * M;
        const float* brow = bins    + (size_t)ry * NBINS;
        if (lane < 63) {
            b_a[r] = brow[2 * lane];
            b_b[r] = brow[2 * lane + 1];
            float2 ww = *reinterpret_cast<const float2*>(wrow + 2 * lane);
            w0[r] = ww.x + 1e-5f;
            w1[r] = ww.y + 1e-5f;
        } else {
            b_a[r] = brow[126];          // feeds lane 62's b_c via wave_shl:1
            b_b[r] = 0.0f; w0[r] = 0.0f; w1[r] = 0.0f;
        }
        rw0[r] = __builtin_amdgcn_rcpf(w0[r]);   // transcendental latency
        rw1[r] = __builtin_amdgcn_rcpf(w1[r]);   // hides under the scans
    }
    __builtin_amdgcn_wave_barrier();

    // ---- phase B: scan -> cdf -> ranks -> params -> paint (3 indep chains) ----
    #pragma unroll
    for (int r = 0; r < RPW; ++r) {
        const float b_c   = dpp_f<0x130, 0xf>(b_a[r]);     // bins[2i+2]
        const float pair  = w0[r] + w1[r];
        const float ps    = wave_iscan_add(pair);          // inclusive prefix
        const float total = __shfl(ps, 63, 64);            // v_readlane
        const float inv   = __builtin_amdgcn_rcpf(total);
        const float excl  = ps - pair;
        const float c0 = excl * inv;                       // cdf[2i]
        const float c1 = (excl + w0[r]) * inv;             // cdf[2i+1]
        const float c2 = ps * inv;                         // cdf[2i+2]

        int g0 = (int)ceilf(fmaf(c0, 256.0f, -1.0f) * 0.5f);
        int g1 = (int)ceilf(fmaf(c1, 256.0f, -1.0f) * 0.5f);
        if (lane == 63) { g0 = NS; g1 = NS; }              // owns no intervals
        g0 = max(g0, 0);
        g1 = max(g1, 0);

        // slope = diff * (dA<1e-5 ? 1 : total*rcp(w)); guard identical to the
        // validated round-8 comparison (dA = c1-c0), rcp moved off-chain.
        const float dA = c1 - c0;
        const float dB = c2 - c1;
        const float fA = (dA < 1e-5f) ? 1.0f : total * rw0[r];
        const float fB = (dB < 1e-5f) ? 1.0f : total * rw1[r];
        const float slA = (b_b[r] - b_a[r]) * fA;
        const float slB = (b_c    - b_b[r]) * fB;
        const float A0  = fmaf(-c0, slA, b_a[r]);          // bl - cl*sl
        const float A1  = fmaf(-c1, slB, b_b[r]);

        int*   seg = &s_all[wave * RPW + r][0];
        float* sA  = reinterpret_cast<float*>(seg + NS);
        float* sB  = reinterpret_cast<float*>(seg + 2 * NS);
        // SoA float2 stores: stride 8B across lanes -> 2-way alias (free)
        *reinterpret_cast<float2*>(&sA[2 * lane]) = make_float2(A0, A1);
        *reinterpret_cast<float2*>(&sB[2 * lane]) = make_float2(slA, slB);
        if (g0 < NS) atomicMax(&seg[g0], 2 * lane);
        if (g1 < NS) atomicMax(&seg[g1], 2 * lane + 1);
    }
    __builtin_amdgcn_wave_barrier();

    // ---- phase C: max-scan K(j), gather, interpolate, store ----
    #pragma unroll
    for (int r = 0; r < RPW; ++r) {
        int*   seg = &s_all[wave * RPW + r][0];
        float* sA  = reinterpret_cast<float*>(seg + NS);
        float* sB  = reinterpret_cast<float*>(seg + 2 * NS);

        const int2 xi = *reinterpret_cast<const int2*>(&seg[2 * lane]);
        const int  m  = wave_iscan_max(max(xi.x, xi.y));
        const int  e  = dpp_i<0x138, 0xf>(m);   // prev pair's max; lane 0 -> 0
        const int  K0 = max(e, xi.x);           // interval of sample 2*lane
        const int  K1 = max(K0, xi.y);          // interval of sample 2*lane+1

        const float A0 = sA[K0], B0 = sB[K0];
        const float A1 = sA[K1], B1 = sB[K1];
        const float u0 = fmaf((float)lane, 0.015625f, 0.00390625f); // (4l+1)/256
        const float u1 = u0 + 0.0078125f;                           // (4l+3)/256
        float2 res;
        res.x = fmaf(u0, B0, A0);
        res.y = fmaf(u1, B1, A1);
        if (valid[r])
            *reinterpret_cast<float2*>(out + (size_t)(base + r) * NS + 2 * lane) = res;
    }
}

extern "C" void kernel_launch(void* const* d_in, const int* in_sizes, int n_in,
                              void* d_out, int out_size, void* d_ws, size_t ws_size,
                              hipStream_t stream) {
    const float* bins    = (const float*)d_in[0];
    const float* weights = (const float*)d_in[1];
    float* out = (float*)d_out;

    const int n_rays = in_sizes[0] / NBINS;
    const int rays_per_block = 4 * RPW;
    const int blocks = (n_rays + rays_per_block - 1) / rays_per_block;
    sample_pdf_rank9<<<blocks, 256, 0, stream>>>(bins, weights, out, n_rays);
}

// Round 10
// 72.423 us; speedup vs baseline: 1.2987x; 1.1265x over previous
//
#include <hip/hip_runtime.h>

// sample_pdf (NeRF, det=True) — rank-scan gather, 3 rays/wave, all-DPP lane
// ops, scalar (SGPR) addressing, branchless loads, interleaved (A,B) params.
//
// u_j=(2j+1)/256 fixed grid; g(c)=ceil(128c-0.5)=#{j:u_j<c} (exact in fp32,
// bit-identical to ceil((256c-1)/2)). Interval k=[cdf[k],cdf[k+1]) owns sample
// slots [g_k,g_{k+1}); K(j)=max{k: g_k<=j} == searchsorted(cdf,u_j,right)-1.
// Per ray: atomicMax-paint interval index k at its start slot (only if g<NS),
// store params (A,B) with sample = A + u*B, wave max-scan forward-fills K(j),
// gather + fma + store.
//
// Lane 63 owns no intervals: its w0=w1=0 exactly -> c0=c1=total*rcp(total),
// and rcp's <=1ulp error keeps c > 127.5/128, so g=128 -> no paint. No
// special-casing needed.
//
// Cross-lane ops are DPP (pure VALU, HW-validated rounds 7-9):
//   scan: row_shr:1/2/4/8 + row_bcast:15 (rows 1,3) + row_bcast:31 (rows 2,3)
//   shfl_down(1)=wave_shl:1 (0x130); shfl_up(1)=wave_shr:1 (0x138, lane0->0)

#define M     126
#define NBINS 127
#define NS    128
#define RPW   3     // rays per wave; 18 KB LDS/block keeps 8 blocks/CU

template<int CTRL, int RM>
__device__ __forceinline__ float dpp_f(float x) {
    return __builtin_bit_cast(float,
        __builtin_amdgcn_update_dpp(0, __builtin_bit_cast(int, x),
                                    CTRL, RM, 0xf, true));
}
template<int CTRL, int RM>
__device__ __forceinline__ int dpp_i(int x) {
    return __builtin_amdgcn_update_dpp(0, x, CTRL, RM, 0xf, true);
}

__device__ __forceinline__ float wave_iscan_add(float x) {
    x += dpp_f<0x111, 0xf>(x);   // row_shr:1
    x += dpp_f<0x112, 0xf>(x);   // row_shr:2
    x += dpp_f<0x114, 0xf>(x);   // row_shr:4
    x += dpp_f<0x118, 0xf>(x);   // row_shr:8
    x += dpp_f<0x142, 0xa>(x);   // row_bcast:15 -> rows 1,3
    x += dpp_f<0x143, 0xc>(x);   // row_bcast:31 -> rows 2,3
    return x;
}
__device__ __forceinline__ int wave_iscan_max(int x) {
    x = max(x, dpp_i<0x111, 0xf>(x));
    x = max(x, dpp_i<0x112, 0xf>(x));
    x = max(x, dpp_i<0x114, 0xf>(x));
    x = max(x, dpp_i<0x118, 0xf>(x));
    x = max(x, dpp_i<0x142, 0xa>(x));
    x = max(x, dpp_i<0x143, 0xc>(x));
    return x;
}

__global__ __launch_bounds__(256) void sample_pdf_rank10(
    const float* __restrict__ bins,
    const float* __restrict__ weights,
    float* __restrict__ out,
    int n_rays)
{
    __shared__ int    s_idx[4 * RPW][NS];
    __shared__ float4 s_P[4 * RPW][NS / 2];  // (A_even, B_even, A_odd, B_odd)

    const int wave = threadIdx.x >> 6;
    const int lane = threadIdx.x & 63;
    const int base = (blockIdx.x * 4 + wave) * RPW;

    // Branchless per-lane load indices (OOB-safe incl. the very last ray).
    const int  i0   = min(2 * lane, 126);      // bins[2i]   (lane63 -> 126)
    const int  i1   = min(2 * lane + 1, 126);  // bins[2i+1]
    const int  iw   = min(2 * lane, 124);      // weights pair
    const bool full = (lane < 63);

    // ---- init paint slots ----
    #pragma unroll
    for (int r = 0; r < RPW; ++r)
        *reinterpret_cast<int2*>(&s_idx[wave * RPW + r][2 * lane]) = make_int2(0, 0);

    // ---- phase A: all global loads up front (scalar row bases) ----
    bool  valid[RPW];
    float b_a[RPW], b_b[RPW], w0[RPW], w1[RPW], rw0[RPW], rw1[RPW];
    #pragma unroll
    for (int r = 0; r < RPW; ++r) {
        const int ry = base + r;
        valid[r] = (ry < n_rays);
        const int ryu = __builtin_amdgcn_readfirstlane(valid[r] ? ry : n_rays - 1);
        const float* wrow = weights + (size_t)ryu * M;   // SGPR base
        const float* brow = bins    + (size_t)ryu * NBINS;
        b_a[r] = brow[i0];
        b_b[r] = brow[i1];
        const float2 ww = *reinterpret_cast<const float2*>(wrow + iw);
        w0[r] = full ? ww.x + 1e-5f : 0.0f;   // lane63: exactly 0
        w1[r] = full ? ww.y + 1e-5f : 0.0f;
        rw0[r] = __builtin_amdgcn_rcpf(w0[r]);  // trans latency hides under scans
        rw1[r] = __builtin_amdgcn_rcpf(w1[r]);  // (inf at lane63: never used)
    }
    __builtin_amdgcn_wave_barrier();

    const float u0 = fmaf((float)lane, 0.015625f, 0.00390625f); // (4l+1)/256
    const float u1 = u0 + 0.0078125f;                           // (4l+3)/256

    // ---- phase B: scan -> cdf -> ranks -> params -> paint (3 indep chains) ----
    #pragma unroll
    for (int r = 0; r < RPW; ++r) {
        const float b_c   = dpp_f<0x130, 0xf>(b_a[r]);     // bins[2i+2]
        const float pair  = w0[r] + w1[r];
        const float ps    = wave_iscan_add(pair);          // inclusive prefix
        const float total = __shfl(ps, 63, 64);            // v_readlane
        const float inv   = __builtin_amdgcn_rcpf(total);
        const float excl  = ps - pair;
        const float c0 = excl * inv;                       // cdf[2i]
        const float c1 = (excl + w0[r]) * inv;             // cdf[2i+1]
        const float c2 = ps * inv;                         // cdf[2i+2]

        const int g0 = (int)ceilf(fmaf(c0, 128.0f, -0.5f));  // exact rank
        const int g1 = (int)ceilf(fmaf(c1, 128.0f, -0.5f));

        const float dA = c1 - c0;
        const float dB = c2 - c1;
        const float fA = (dA < 1e-5f) ? 1.0f : total * rw0[r];
        const float fB = (dB < 1e-5f) ? 1.0f : total * rw1[r];
        const float slA = (b_b[r] - b_a[r]) * fA;
        const float slB = (b_c    - b_b[r]) * fB;
        const float A0  = fmaf(-c0, slA, b_a[r]);          // bl - cl*sl
        const float A1  = fmaf(-c1, slB, b_b[r]);

        const int seg = wave * RPW + r;
        s_P[seg][lane] = make_float4(A0, slA, A1, slB);    // one ds_write_b128
        if (g0 < NS) atomicMax(&s_idx[seg][g0], 2 * lane);
        if (g1 < NS) atomicMax(&s_idx[seg][g1], 2 * lane + 1);
    }
    __builtin_amdgcn_wave_barrier();

    // ---- phase C: max-scan K(j), gather (2x b64), interpolate, store ----
    #pragma unroll
    for (int r = 0; r < RPW; ++r) {
        const int seg = wave * RPW + r;
        const int2 xi = *reinterpret_cast<const int2*>(&s_idx[seg][2 * lane]);
        const int  m  = wave_iscan_max(max(xi.x, xi.y));
        const int  e  = dpp_i<0x138, 0xf>(m);   // prev pair's max; lane 0 -> 0
        const int  K0 = max(e, xi.x);           // interval of sample 2*lane
        const int  K1 = max(K0, xi.y);          // interval of sample 2*lane+1

        const float2* P = reinterpret_cast<const float2*>(&s_P[seg][0]);
        const float2 p0 = P[K0];                // (A, B): sample = A + u*B
        const float2 p1 = P[K1];
        float2 res;
        res.x = fmaf(u0, p0.y, p0.x);
        res.y = fmaf(u1, p1.y, p1.x);
        if (valid[r]) {
            const int ro = __builtin_amdgcn_readfirstlane(base + r);
            *reinterpret_cast<float2*>(out + (size_t)ro * NS + 2 * lane) = res;
        }
    }
}

extern "C" void kernel_launch(void* const* d_in, const int* in_sizes, int n_in,
                              void* d_out, int out_size, void* d_ws, size_t ws_size,
                              hipStream_t stream) {
    const float* bins    = (const float*)d_in[0];
    const float* weights = (const float*)d_in[1];
    float* out = (float*)d_out;

    const int n_rays = in_sizes[0] / NBINS;
    const int rays_per_block = 4 * RPW;
    const int blocks = (n_rays + rays_per_block - 1) / rays_per_block;
    sample_pdf_rank10<<<blocks, 256, 0, stream>>>(bins, weights, out, n_rays);
}